// Round 1
// baseline (200.309 us; speedup 1.0000x reference)
//
#include <hip/hip_runtime.h>
#include <hip/hip_bf16.h>
#include <math.h>

#define B_  16
#define T_  2048
#define C_  384
#define DK_ 64

typedef short bf16x8 __attribute__((ext_vector_type(8)));
typedef float f32x4  __attribute__((ext_vector_type(4)));
typedef unsigned short u16;
typedef unsigned int   u32;

// fp32 -> bf16 round-to-nearest-even (finite inputs)
__device__ __forceinline__ u16 f2bf(float f) {
  u32 u = __builtin_bit_cast(u32, f);
  u32 r = u + 0x7FFFu + ((u >> 16) & 1u);
  return (u16)(r >> 16);
}

__device__ __forceinline__ void gld_lds16(const void* g, void* l) {
  __builtin_amdgcn_global_load_lds(
      (const __attribute__((address_space(1))) void*)g,
      (__attribute__((address_space(3))) void*)l, 16, 0, 0);
}

__device__ __forceinline__ f32x4 mfma16(bf16x8 a, bf16x8 b, f32x4 c) {
  return __builtin_amdgcn_mfma_f32_16x16x32_bf16(a, b, c, 0, 0, 0);
}

// ---------------------------------------------------------------------------
// Kernel 1: build swizzled bf16 W^T (rows: 0..63 WQ*scale, 64..127 WK, 128..191 WV)
// Layout: row n (0..191) x 48 16B-granules; phys granule gp holds logical gp^(n&7).
// Wt[n][k] = W[k][n].  Scale for Q rows: (1/8)*log2(e)  (exp2-domain softmax).
// ---------------------------------------------------------------------------
__global__ __launch_bounds__(256) void prep_w_k(
    const float* __restrict__ WQ, const float* __restrict__ WK,
    const float* __restrict__ WV, u16* __restrict__ wt) {
  int gi = blockIdx.x * 256 + threadIdx.x;
  if (gi >= 192 * 48) return;
  int n  = gi / 48;
  int gp = gi - n * 48;
  int gl = gp ^ (n & 7);           // logical granule (low-3-bit XOR swizzle)
  int k0 = gl * 8;
  const float* W = (n < 64) ? WQ : ((n < 128) ? WK : WV);
  int   nn = n & 63;
  float sc = (n < 64) ? 0.18033688011112042f : 1.0f;  // (1/sqrt(64))*log2(e)
  bf16x8 o;
#pragma unroll
  for (int j = 0; j < 8; ++j)
    o[j] = (short)f2bf(W[(size_t)(k0 + j) * DK_ + nn] * sc);
  *(bf16x8*)(wt + (size_t)gi * 8) = o;
}

// ---------------------------------------------------------------------------
// Kernel 2: fused QKV projection.  q,k,v bf16 [B*T][64].
// 128 rows/block, 8 waves (each wave: 16 rows x 192 cols), K=384 in 12 steps.
// A-frags loaded straight from global x (coalesced); Wt fully LDS-resident.
// ---------------------------------------------------------------------------
__global__ __launch_bounds__(512) void proj_k(
    const float* __restrict__ x, const u16* __restrict__ wt,
    u16* __restrict__ qo, u16* __restrict__ ko, u16* __restrict__ vo) {
  __shared__ u16 ldsW[192 * 48 * 8];  // 147456 B
  int tid = threadIdx.x;
  int w = tid >> 6, lane = tid & 63, l15 = lane & 15, lg = lane >> 4;

  // stage all of Wt: 9216 granules / 512 threads = 18 iters (linear copy; src pre-swizzled)
#pragma unroll
  for (int it = 0; it < 18; ++it) {
    int idx = it * 512 + tid;
    gld_lds16(wt + (size_t)idx * 8, (char*)ldsW + (size_t)(it * 512 + w * 64) * 16);
  }
  __syncthreads();

  int row0 = blockIdx.x * 128 + w * 16;
  f32x4 acc[12];
#pragma unroll
  for (int i = 0; i < 12; ++i) acc[i] = (f32x4){0.f, 0.f, 0.f, 0.f};

  const float* xp0 = x + (size_t)(row0 + l15) * C_ + lg * 8;
#pragma unroll
  for (int ks = 0; ks < 12; ++ks) {
    const float* xp = xp0 + ks * 32;
    float4 alo = *(const float4*)xp;
    float4 ahi = *(const float4*)(xp + 4);
    bf16x8 af;
    af[0] = (short)f2bf(alo.x); af[1] = (short)f2bf(alo.y);
    af[2] = (short)f2bf(alo.z); af[3] = (short)f2bf(alo.w);
    af[4] = (short)f2bf(ahi.x); af[5] = (short)f2bf(ahi.y);
    af[6] = (short)f2bf(ahi.z); af[7] = (short)f2bf(ahi.w);
#pragma unroll
    for (int nt = 0; nt < 12; ++nt) {
      int n  = nt * 16 + l15;
      int gp = (ks * 4 + lg) ^ (n & 7);
      bf16x8 bfg = *(const bf16x8*)((const char*)ldsW + (size_t)(n * 48 + gp) * 16);
      acc[nt] = mfma16(af, bfg, acc[nt]);
    }
  }
  // epilogue: C/D layout col=l15(+16*nt), row=lg*4+r
#pragma unroll
  for (int nt = 0; nt < 12; ++nt) {
    int col = nt * 16 + l15;
    u16* dst = (col < 64) ? qo : ((col < 128) ? ko : vo);
    int c = col & 63;
#pragma unroll
    for (int r = 0; r < 4; ++r) {
      int grow = row0 + lg * 4 + r;
      dst[(size_t)grow * DK_ + c] = f2bf(acc[nt][r]);
    }
  }
}

// ---------------------------------------------------------------------------
// Kernel 3: causal flash attention.  One block = (batch b, q-tile of 64 rows).
// 4 waves x 16 q-rows.  KV tiles of 64.  exp2-domain online softmax
// (log2(e)/8 folded into Q at projection time).
// ---------------------------------------------------------------------------
__global__ __launch_bounds__(256) void flash_k(
    const u16* __restrict__ q, const u16* __restrict__ k,
    const u16* __restrict__ v, float* __restrict__ out) {
  __shared__ u16 ldsK[64 * 64];    // K tile  [kv][d], granule-swizzled (g^(kv&7))
  __shared__ u16 ldsVT[64 * 64];   // V^T tile [d][kv], swizzled ((d&7)^((d>>3)&7))
  __shared__ u16 ldsP[4 * 16 * 64];// per-wave P [16 q][64 kv], swizzled (row&7)

  int tid = threadIdx.x;
  int w = tid >> 6, lane = tid & 63, l15 = lane & 15, lg = lane >> 4;
  int bb = blockIdx.x & 15;
  int qt = 31 - (blockIdx.x >> 4);      // longest q-tiles first (LPT balance)
  int qrow0 = bb * T_ + qt * 64;

  // Q fragments (bf16, scale pre-folded): row = l15, k = lg*8 + j (+32 for slice 1)
  const u16* qp = q + (size_t)(qrow0 + w * 16 + l15) * DK_ + lg * 8;
  bf16x8 qf0 = *(const bf16x8*)qp;
  bf16x8 qf1 = *(const bf16x8*)(qp + 32);

  f32x4 o[4];
#pragma unroll
  for (int i = 0; i < 4; ++i) o[i] = (f32x4){0.f, 0.f, 0.f, 0.f};
  float m[4], lsum[4];
#pragma unroll
  for (int r = 0; r < 4; ++r) { m[r] = -INFINITY; lsum[r] = 0.f; }

  char* pbuf = (char*)ldsP + w * 2048;

  for (int t = 0; t <= qt; ++t) {
    __syncthreads();                     // prev-iter compute done before restage
    int kvb = bb * T_ + t * 64;

    // ---- stage K tile via global_load_lds, source pre-swizzled, LDS linear
#pragma unroll
    for (int it = 0; it < 2; ++it) {
      int i = it * 256 + tid;
      int r = i >> 3, s = i & 7;
      gld_lds16(k + (size_t)(kvb + r) * DK_ + ((s ^ (r & 7)) * 8),
                (char*)ldsK + (it * 256 + w * 64) * 16);
    }
    // ---- stage V^T (reg transpose; u32 = {V[kv][d], V[kv+1][d]})
    {
      int kv = (tid >> 3) * 2;
      int d0 = (tid & 7) * 8;
      bf16x8 r0 = *(const bf16x8*)(v + (size_t)(kvb + kv) * DK_ + d0);
      bf16x8 r1 = *(const bf16x8*)(v + (size_t)(kvb + kv + 1) * DK_ + d0);
#pragma unroll
      for (int j = 0; j < 8; ++j) {
        int d = d0 + j;
        u32 val = (u32)(u16)r0[j] | ((u32)(u16)r1[j] << 16);
        int off = d * 128 + ((kv * 2) ^ ((((d & 7) ^ ((d >> 3) & 7))) << 4));
        *(u32*)((char*)ldsVT + off) = val;
      }
    }
    __syncthreads();

    // ---- S = Q K^T  (per wave: 16 q-rows x 64 kv)
    f32x4 sa[4];
#pragma unroll
    for (int nt = 0; nt < 4; ++nt) {
      int n = nt * 16 + l15;             // kv row in tile
      bf16x8 kb0 = *(const bf16x8*)((char*)ldsK + (n * 8 + ((lg) ^ (n & 7))) * 16);
      bf16x8 kb1 = *(const bf16x8*)((char*)ldsK + (n * 8 + ((4 + lg) ^ (n & 7))) * 16);
      sa[nt] = (f32x4){0.f, 0.f, 0.f, 0.f};
      sa[nt] = mfma16(qf0, kb0, sa[nt]);
      sa[nt] = mfma16(qf1, kb1, sa[nt]);
    }

    // ---- causal mask (diagonal tile only)
    if (t == qt) {
      int rowt = w * 16 + lg * 4;
#pragma unroll
      for (int nt = 0; nt < 4; ++nt) {
        int colt = nt * 16 + l15;
#pragma unroll
        for (int r = 0; r < 4; ++r)
          if (colt > rowt + r) sa[nt][r] = -INFINITY;
      }
    }

    // ---- online softmax (exp2 domain); rows live on 16-lane groups
#pragma unroll
    for (int r = 0; r < 4; ++r) {
      float mx = fmaxf(fmaxf(sa[0][r], sa[1][r]), fmaxf(sa[2][r], sa[3][r]));
      mx = fmaxf(mx, __shfl_xor(mx, 1));
      mx = fmaxf(mx, __shfl_xor(mx, 2));
      mx = fmaxf(mx, __shfl_xor(mx, 4));
      mx = fmaxf(mx, __shfl_xor(mx, 8));
      float mn = fmaxf(m[r], mx);
      float al = exp2f(m[r] - mn);       // m=-inf first tile -> al=0
      m[r] = mn;
      float rs = 0.f;
#pragma unroll
      for (int nt = 0; nt < 4; ++nt) {
        float p = exp2f(sa[nt][r] - mn);
        sa[nt][r] = p;
        rs += p;
      }
      rs += __shfl_xor(rs, 1); rs += __shfl_xor(rs, 2);
      rs += __shfl_xor(rs, 4); rs += __shfl_xor(rs, 8);
      lsum[r] = lsum[r] * al + rs;
      o[0][r] *= al; o[1][r] *= al; o[2][r] *= al; o[3][r] *= al;
    }

    // ---- P -> bf16 -> per-wave LDS (pair-packed u32, even lanes store)
#pragma unroll
    for (int nt = 0; nt < 4; ++nt) {
#pragma unroll
      for (int r = 0; r < 4; ++r) {
        float pv = sa[nt][r];
        float po = __shfl_xor(pv, 1);
        u32 pk = (lane & 1) ? ((u32)f2bf(po) | ((u32)f2bf(pv) << 16))
                            : ((u32)f2bf(pv) | ((u32)f2bf(po) << 16));
        if (!(lane & 1)) {
          int row = lg * 4 + r;
          int off = row * 128 + ((((nt * 16 + l15) & ~1) * 2) ^ ((row & 7) << 4));
          *(u32*)(pbuf + off) = pk;
        }
      }
    }

    // ---- O += P V   (A-frags from pbuf, B-frags from swizzled V^T)
    bf16x8 pf0, pf1;
    {
      int row = l15;
      int sw = (row & 7) << 4;
      pf0 = *(const bf16x8*)(pbuf + row * 128 + (((lg * 8) * 2) ^ sw));
      pf1 = *(const bf16x8*)(pbuf + row * 128 + (((32 + lg * 8) * 2) ^ sw));
    }
#pragma unroll
    for (int dt = 0; dt < 4; ++dt) {
      int d = dt * 16 + l15;
      int swv = ((d & 7) ^ ((d >> 3) & 7)) << 4;
      bf16x8 vf0 = *(const bf16x8*)((char*)ldsVT + d * 128 + (((lg * 8) * 2) ^ swv));
      bf16x8 vf1 = *(const bf16x8*)((char*)ldsVT + d * 128 + (((32 + lg * 8) * 2) ^ swv));
      o[dt] = mfma16(pf0, vf0, o[dt]);
      o[dt] = mfma16(pf1, vf1, o[dt]);
    }
  }

  // ---- epilogue: normalize, fp32 store
  float rl[4];
#pragma unroll
  for (int r = 0; r < 4; ++r) rl[r] = 1.f / lsum[r];
#pragma unroll
  for (int dt = 0; dt < 4; ++dt)
#pragma unroll
    for (int r = 0; r < 4; ++r)
      out[(size_t)(qrow0 + w * 16 + lg * 4 + r) * DK_ + dt * 16 + l15] =
          o[dt][r] * rl[r];
}

// ---------------------------------------------------------------------------
extern "C" void kernel_launch(void* const* d_in, const int* in_sizes, int n_in,
                              void* d_out, int out_size, void* d_ws, size_t ws_size,
                              hipStream_t stream) {
  const float* x  = (const float*)d_in[0];
  const float* WQ = (const float*)d_in[1];
  const float* WK = (const float*)d_in[2];
  const float* WV = (const float*)d_in[3];
  float* out = (float*)d_out;

  char* ws = (char*)d_ws;
  u16* qb = (u16*)(ws);
  u16* kb = (u16*)(ws + ((size_t)4 << 20));
  u16* vb = (u16*)(ws + ((size_t)8 << 20));
  u16* wt = (u16*)(ws + ((size_t)12 << 20));

  prep_w_k<<<36, 256, 0, stream>>>(WQ, WK, WV, wt);
  proj_k<<<256, 512, 0, stream>>>(x, wt, qb, kb, vb);
  flash_k<<<512, 256, 0, stream>>>(qb, kb, vb, out);
}